// Round 1
// 1546.333 us; speedup vs baseline: 1.4506x; 1.4506x over previous
//
#include <hip/hip_runtime.h>
#include <stdint.h>

#define N_NODES 2000
#define N_EDGES 64000
#define EDIM 16
#define ENH 128
#define HD 64
#define T_STEPS 8
#define HH 4096  // HD*HD

typedef unsigned short u16;
typedef __bf16 bf16x8 __attribute__((ext_vector_type(8)));
typedef float float4v __attribute__((ext_vector_type(4)));

// ---- static device scratch (rewritten every call); d_ws holds Aq + x/m ----
__device__ u16   g_h1_hi[(size_t)N_EDGES * ENH];   // 16.4 MB
__device__ u16   g_h1_lo[(size_t)N_EDGES * ENH];   // 16.4 MB
__device__ u16   g_w2t_hi[HH * ENH];               // 1 MB
__device__ u16   g_w2t_lo[HH * ENH];               // 1 MB
__device__ float g_scale[(N_EDGES / 16) * 32];     // per 16-edge x 128-n tile scale

__device__ __forceinline__ float b2f(u16 h) {
    union { unsigned int u; float f; } v; v.u = ((unsigned int)h) << 16; return v.f;
}
__device__ __forceinline__ u16 f2b(float f) {
    union { float f; unsigned int u; } v; v.f = f;
    unsigned int u = v.u;
    return (u16)((u + 0x7FFFu + ((u >> 16) & 1u)) >> 16);  // RNE
}

// ---- x fp32 -> ping-pong buffer; also zero m for the first step's atomics ----
__global__ void k_xinit(const float* __restrict__ xin, float* __restrict__ x0,
                        float* __restrict__ m) {
    int i = blockIdx.x * 256 + threadIdx.x;
    if (i < N_NODES * HD) { x0[i] = xin[i]; m[i] = 0.f; }
}

// ---- h1 = relu(ef @ W1 + b1) in fp32, stored as exact bf16 hi+lo split ----
__global__ __launch_bounds__(256) void k_h1(const float* __restrict__ edge_data,
                                            const int* __restrict__ edges,
                                            const float* __restrict__ W1,
                                            const float* __restrict__ b1) {
    int tid = threadIdx.x;
    int e = blockIdx.x * 2 + (tid >> 7);
    int c = tid & 127;
    int src = edges[2 * e], tgt = edges[2 * e + 1];
    const float* ef = edge_data + ((size_t)src * N_NODES + (size_t)tgt) * EDIM;
    float acc = b1[c];
#pragma unroll
    for (int k = 0; k < EDIM; k++)
        acc += ef[k] * W1[k * ENH + c];
    float v = fmaxf(acc, 0.f);
    u16 hi = f2b(v);
    size_t idx = (size_t)e * ENH + c;
    g_h1_hi[idx] = hi;
    g_h1_lo[idx] = f2b(v - b2f(hi));
}

// ---- W2 (128 x 4096) -> transposed bf16 hi/lo planes (k-contiguous) ----
__global__ void k_w2t(const float* __restrict__ W2) {
    int idx = blockIdx.x * 256 + threadIdx.x;  // = n*128 + k
    int n = idx >> 7, k = idx & 127;
    float v = W2[(size_t)k * HH + n];
    u16 hi = f2b(v);
    g_w2t_hi[idx] = hi;
    g_w2t_lo[idx] = f2b(v - b2f(hi));
}

// ---- A = relu(h1 @ W2 + b2) via 3-way split MFMA.
// LDS-staged 128(M) x 128(N) block tile, BK=64 two-phase, 2x2 wave grid
// (each wave 64x64 out). Padded LDS stride (72 u16 = 144 B) makes both the
// staged ds_write_b128 and the fragment ds_read_b128 bank-uniform.
// Quantize per 16-edge x 128-n tile to u16 (scale combined across the two
// column waves -> bit-identical to previous kernel). Epilogue: LDS-staged
// coalesced dwordx4 stores (LDS reused, 136-u16 stride avoids conflicts). ----
#define LDK 72   // 64 + 8 pad (u16)
#define STK 136  // 128 + 8 pad (u16), keeps 16B alignment per row (272 B)

__global__ __launch_bounds__(256, 2) void k_gemmA(const float* __restrict__ b2,
                                                  u16* __restrict__ Aq) {
    __shared__ __align__(16) u16 smem[4 * 128 * LDK];  // 73728 B
    __shared__ float redmax[2][4][2];                  // [wm][mi][wn]
    u16 (*sAh)[LDK] = (u16(*)[LDK])smem;
    u16 (*sAl)[LDK] = (u16(*)[LDK])(smem + 128 * LDK);
    u16 (*sBh)[LDK] = (u16(*)[LDK])(smem + 2 * 128 * LDK);
    u16 (*sBl)[LDK] = (u16(*)[LDK])(smem + 3 * 128 * LDK);
    u16 (*st)[STK]  = (u16(*)[STK])smem;               // 34816 B, fits

    // bijective XCD swizzle: 16000 blocks = 8 XCDs x 2000; consecutive
    // logical ids (which share an h1 tile, cb-fast) stay on one XCD.
    int bid = (blockIdx.x & 7) * 2000 + (blockIdx.x >> 3);
    int cb = bid & 31;        // col-block fast: consecutive blocks share h1 tile
    int rb = bid >> 5;        // 0..499
    int m0 = rb * 128, n0 = cb * 128;
    int t = threadIdx.x;
    int w = t >> 6, l = t & 63;
    int wm = w >> 1, wn = w & 1;          // 2x2 wave grid
    int quad = l >> 4, lr = l & 15;

    float4v acc[4][4];
#pragma unroll
    for (int mi = 0; mi < 4; mi++)
#pragma unroll
        for (int ni = 0; ni < 4; ni++) acc[mi][ni] = (float4v){0.f, 0.f, 0.f, 0.f};

#pragma unroll
    for (int kc = 0; kc < 2; kc++) {
        if (kc) __syncthreads();  // previous phase's reads done before overwrite
        // stage: per plane 128 rows x 64 u16 (128 B) = 1024 x 16B chunks
#pragma unroll
        for (int rnd = 0; rnd < 4; rnd++) {
            int c = rnd * 256 + t;
            int row = c >> 3, c8 = c & 7;       // 8 x 16B chunks per row
            size_t gA = ((size_t)(m0 + row) << 7) + (kc << 6) + (c8 << 3);
            size_t gB = ((size_t)(n0 + row) << 7) + (kc << 6) + (c8 << 3);
            *(uint4*)&sAh[row][c8 * 8] = *(const uint4*)(g_h1_hi + gA);
            *(uint4*)&sAl[row][c8 * 8] = *(const uint4*)(g_h1_lo + gA);
            *(uint4*)&sBh[row][c8 * 8] = *(const uint4*)(g_w2t_hi + gB);
            *(uint4*)&sBl[row][c8 * 8] = *(const uint4*)(g_w2t_lo + gB);
        }
        __syncthreads();
#pragma unroll
        for (int kq = 0; kq < 2; kq++) {
            int ko = kq * 32 + quad * 8;
            bf16x8 ah[4], al[4], bh[4], bl[4];
#pragma unroll
            for (int i = 0; i < 4; i++) {
                ah[i] = *(const bf16x8*)&sAh[wm * 64 + i * 16 + lr][ko];
                al[i] = *(const bf16x8*)&sAl[wm * 64 + i * 16 + lr][ko];
                bh[i] = *(const bf16x8*)&sBh[wn * 64 + i * 16 + lr][ko];
                bl[i] = *(const bf16x8*)&sBl[wn * 64 + i * 16 + lr][ko];
            }
#pragma unroll
            for (int mi = 0; mi < 4; mi++)
#pragma unroll
                for (int ni = 0; ni < 4; ni++) {
                    acc[mi][ni] = __builtin_amdgcn_mfma_f32_16x16x32_bf16(ah[mi], bh[ni], acc[mi][ni], 0, 0, 0);
                    acc[mi][ni] = __builtin_amdgcn_mfma_f32_16x16x32_bf16(ah[mi], bl[ni], acc[mi][ni], 0, 0, 0);
                    acc[mi][ni] = __builtin_amdgcn_mfma_f32_16x16x32_bf16(al[mi], bh[ni], acc[mi][ni], 0, 0, 0);
                }
        }
    }

    // bias + relu in place; per-(16-row x 64-col) wave max, per mi
    float wmax[4];
#pragma unroll
    for (int mi = 0; mi < 4; mi++) {
        float lm = 0.f;
#pragma unroll
        for (int ni = 0; ni < 4; ni++) {
            float bias = b2[n0 + wn * 64 + ni * 16 + lr];
#pragma unroll
            for (int r = 0; r < 4; r++) {
                float v = fmaxf(acc[mi][ni][r] + bias, 0.f);
                acc[mi][ni][r] = v;
                lm = fmaxf(lm, v);
            }
        }
#pragma unroll
        for (int ofs = 32; ofs > 0; ofs >>= 1)
            lm = fmaxf(lm, __shfl_xor(lm, ofs));
        wmax[mi] = lm;
    }
    if (l == 0) {
#pragma unroll
        for (int mi = 0; mi < 4; mi++) redmax[wm][mi][wn] = wmax[mi];
    }
    __syncthreads();  // redmax visible; also: all MFMA reads of smem done

    float inv[4];
#pragma unroll
    for (int mi = 0; mi < 4; mi++) {
        float cm = fmaxf(redmax[wm][mi][0], redmax[wm][mi][1]);
        inv[mi] = (cm > 0.f) ? (65535.f / cm) : 0.f;
        if (wn == 0 && l == 0)
            g_scale[(size_t)((m0 + wm * 64 + mi * 16) >> 4) * 32 + cb] = cm * (1.f / 65535.f);
    }

    // quantize into LDS staging tile (128 x 128, padded stride)
#pragma unroll
    for (int mi = 0; mi < 4; mi++)
#pragma unroll
        for (int ni = 0; ni < 4; ni++) {
            int col = wn * 64 + ni * 16 + lr;
#pragma unroll
            for (int r = 0; r < 4; r++) {
                u16 q = (u16)fminf(acc[mi][ni][r] * inv[mi] + 0.5f, 65535.f);
                st[wm * 64 + mi * 16 + quad * 4 + r][col] = q;
            }
        }
    __syncthreads();

    // coalesced stores: 128 rows x 256 B, 2048 chunks / 256 threads
#pragma unroll
    for (int rnd = 0; rnd < 8; rnd++) {
        int c = rnd * 256 + t;
        int row = c >> 4, ch = c & 15;
        uint4 v = *(const uint4*)&st[row][ch * 8];
        *(uint4*)(Aq + (size_t)(m0 + row) * HH + n0 + ch * 8) = v;
    }
}

// ---- per step: one wave per edge, fully-coalesced Aq reads + 8-lane
// butterfly reduction. msg = A_e @ x[src], scatter to m[tgt], m[src]. ----
__global__ __launch_bounds__(256) void k_edge(const u16* __restrict__ Aq,
                                              const float* __restrict__ xcur,
                                              const int* __restrict__ edges,
                                              float* __restrict__ m) {
    int gid = blockIdx.x * 256 + threadIdx.x;
    int e = gid >> 6;
    int l = gid & 63;
    int src = edges[2 * e], tgt = edges[2 * e + 1];
    // lane l's x chunk: cols [(l&7)*8, +8) — invariant across t
    const float4* xp = (const float4*)(xcur + (size_t)src * HD + (l & 7) * 8);
    float4 xa = xp[0], xb = xp[1];
    const uint4* ap = (const uint4*)(Aq + (size_t)e * HH);  // 8KB row-major edge matrix
    float msgv = 0.f;
#pragma unroll
    for (int t = 0; t < 8; t++) {
        // lane l loads flat u16 [t*512 + l*8, +8): row 8t+(l>>3), cols (l&7)*8..+8
        // uint4 index = (t*512 + l*8)/8 = t*64 + l   (uint4 = 8 u16!)
        uint4 a = ap[t * 64 + l];
        float p;
        p  = (float)(a.x & 0xFFFFu) * xa.x + (float)(a.x >> 16) * xa.y;
        p += (float)(a.y & 0xFFFFu) * xa.z + (float)(a.y >> 16) * xa.w;
        p += (float)(a.z & 0xFFFFu) * xb.x + (float)(a.z >> 16) * xb.y;
        p += (float)(a.w & 0xFFFFu) * xb.z + (float)(a.w >> 16) * xb.w;
        // reduce over the 8 lanes sharing this row (same l>>3)
        p += __shfl_xor(p, 1);
        p += __shfl_xor(p, 2);
        p += __shfl_xor(p, 4);
        msgv = ((l & 7) == t) ? p : msgv;
    }
    int r = (l & 7) * 8 + (l >> 3);  // row this lane ended up owning (bijection)
    float scale = g_scale[(e >> 4) * 32 + (r >> 1)];
    float msg = msgv * scale;
    unsafeAtomicAdd(&m[(size_t)tgt * HD + r], msg);
    if (src != tgt) unsafeAtomicAdd(&m[(size_t)src * HD + r], msg);
}

// ---- per step: GRU update per node; re-zero m for next step; fp32 out ----
__global__ __launch_bounds__(64) void k_gru(const float* __restrict__ xcur,
                                            float* __restrict__ m,
                                            const float* __restrict__ W_ih,
                                            const float* __restrict__ W_hh,
                                            const float* __restrict__ b_ih,
                                            const float* __restrict__ b_hh,
                                            float* __restrict__ xnext,
                                            float* __restrict__ out, int write_out) {
    int v = blockIdx.x, j = threadIdx.x;
    __shared__ float xs[HD], ms[HD];
    xs[j] = xcur[v * HD + j];
    ms[j] = m[v * HD + j];
    __syncthreads();
    float gir = b_ih[j], giz = b_ih[64 + j], gin = b_ih[128 + j];
    float ghr = b_hh[j], ghz = b_hh[64 + j], ghn = b_hh[128 + j];
    for (int k = 0; k < HD; k++) {
        float xk = xs[k], mk = ms[k];
        const float* wi_x = W_ih + k * 192;
        const float* wi_m = W_ih + (64 + k) * 192;
        const float* wh = W_hh + k * 192;
        gir += xk * wi_x[j] + mk * wi_m[j];
        giz += xk * wi_x[64 + j] + mk * wi_m[64 + j];
        gin += xk * wi_x[128 + j] + mk * wi_m[128 + j];
        ghr += xk * wh[j];
        ghz += xk * wh[64 + j];
        ghn += xk * wh[128 + j];
    }
    float r = 1.f / (1.f + __expf(-(gir + ghr)));
    float z = 1.f / (1.f + __expf(-(giz + ghz)));
    float n = tanhf(gin + r * ghn);
    float xn = (1.f - z) * n + z * xs[j];
    xnext[v * HD + j] = xn;
    m[v * HD + j] = 0.f;  // ready for next step's atomics
    if (write_out) out[v * HD + j] = xn;
}

extern "C" void kernel_launch(void* const* d_in, const int* in_sizes, int n_in,
                              void* d_out, int out_size, void* d_ws, size_t ws_size,
                              hipStream_t stream) {
    (void)in_sizes; (void)n_in; (void)out_size; (void)ws_size;
    const float* x_in      = (const float*)d_in[0];
    // d_in[1] adj: unused (zeros)
    const float* edge_data = (const float*)d_in[2];
    const int*   edges     = (const int*)d_in[3];
    // d_in[4] T: fixed at 8 (module constant in reference)
    const float* W1   = (const float*)d_in[5];
    const float* b1   = (const float*)d_in[6];
    const float* W2   = (const float*)d_in[7];
    const float* b2   = (const float*)d_in[8];
    const float* W_ih = (const float*)d_in[9];
    const float* W_hh = (const float*)d_in[10];
    const float* b_ih = (const float*)d_in[11];
    const float* b_hh = (const float*)d_in[12];
    float* out = (float*)d_out;

    // d_ws layout: Aq (524.3 MB) + x ping-pong + m (1.5 MB)
    char* ws = (char*)d_ws;
    u16* Aq = (u16*)ws;
    size_t off = (size_t)N_EDGES * HH * sizeof(u16);
    float* xb0 = (float*)(ws + off); off += (size_t)N_NODES * HD * sizeof(float);
    float* xb1 = (float*)(ws + off); off += (size_t)N_NODES * HD * sizeof(float);
    float* m   = (float*)(ws + off); off += (size_t)N_NODES * HD * sizeof(float);

    k_xinit<<<(N_NODES * HD + 255) / 256, 256, 0, stream>>>(x_in, xb0, m);
    k_h1<<<N_EDGES / 2, 256, 0, stream>>>(edge_data, edges, W1, b1);
    k_w2t<<<(HH * 128) / 256, 256, 0, stream>>>(W2);
    k_gemmA<<<(N_EDGES / 128) * (HH / 128), 256, 0, stream>>>(b2, Aq);

    float* bufs[2] = {xb0, xb1};
    for (int t = 0; t < T_STEPS; t++) {
        k_edge<<<(N_EDGES * 64) / 256, 256, 0, stream>>>(Aq, bufs[t & 1], edges, m);
        k_gru<<<N_NODES, 64, 0, stream>>>(bufs[t & 1], m, W_ih, W_hh, b_ih, b_hh,
                                          bufs[(t + 1) & 1], out,
                                          (t == T_STEPS - 1) ? 1 : 0);
    }
}

// Round 4
// 1456.685 us; speedup vs baseline: 1.5399x; 1.0615x over previous
//
#include <hip/hip_runtime.h>
#include <stdint.h>

#define N_NODES 2000
#define N_EDGES 64000
#define EDIM 16
#define ENH 128
#define HD 64
#define T_STEPS 8
#define HH 4096  // HD*HD

typedef unsigned short u16;
typedef __bf16 bf16x8 __attribute__((ext_vector_type(8)));
typedef float float4v __attribute__((ext_vector_type(4)));
typedef unsigned int uint4v __attribute__((ext_vector_type(4)));  // native vec for nontemporal builtins

// ---- static device scratch (rewritten every call); d_ws holds Aq + x/m ----
__device__ u16   g_h1_hi[(size_t)N_EDGES * ENH];   // 16.4 MB
__device__ u16   g_h1_lo[(size_t)N_EDGES * ENH];   // 16.4 MB
__device__ u16   g_w2t_hi[HH * ENH];               // 1 MB
__device__ u16   g_w2t_lo[HH * ENH];               // 1 MB
__device__ float g_scale[(N_EDGES / 16) * 32];     // per 16-edge x 128-n tile scale

__device__ __forceinline__ float b2f(u16 h) {
    union { unsigned int u; float f; } v; v.u = ((unsigned int)h) << 16; return v.f;
}
__device__ __forceinline__ u16 f2b(float f) {
    union { float f; unsigned int u; } v; v.f = f;
    unsigned int u = v.u;
    return (u16)((u + 0x7FFFu + ((u >> 16) & 1u)) >> 16);  // RNE
}

// ---- x fp32 -> ping-pong buffer; also zero m for the first step's atomics ----
__global__ void k_xinit(const float* __restrict__ xin, float* __restrict__ x0,
                        float* __restrict__ m) {
    int i = blockIdx.x * 256 + threadIdx.x;
    if (i < N_NODES * HD) { x0[i] = xin[i]; m[i] = 0.f; }
}

// ---- h1 = relu(ef @ W1 + b1) in fp32, stored as exact bf16 hi+lo split ----
__global__ __launch_bounds__(256) void k_h1(const float* __restrict__ edge_data,
                                            const int* __restrict__ edges,
                                            const float* __restrict__ W1,
                                            const float* __restrict__ b1) {
    int tid = threadIdx.x;
    int e = blockIdx.x * 2 + (tid >> 7);
    int c = tid & 127;
    int src = edges[2 * e], tgt = edges[2 * e + 1];
    const float* ef = edge_data + ((size_t)src * N_NODES + (size_t)tgt) * EDIM;
    float acc = b1[c];
#pragma unroll
    for (int k = 0; k < EDIM; k++)
        acc += ef[k] * W1[k * ENH + c];
    float v = fmaxf(acc, 0.f);
    u16 hi = f2b(v);
    size_t idx = (size_t)e * ENH + c;
    g_h1_hi[idx] = hi;
    g_h1_lo[idx] = f2b(v - b2f(hi));
}

// ---- W2 (128 x 4096) -> transposed bf16 hi/lo planes (k-contiguous) ----
__global__ void k_w2t(const float* __restrict__ W2) {
    int idx = blockIdx.x * 256 + threadIdx.x;  // = n*128 + k
    int n = idx >> 7, k = idx & 127;
    float v = W2[(size_t)k * HH + n];
    u16 hi = f2b(v);
    g_w2t_hi[idx] = hi;
    g_w2t_lo[idx] = f2b(v - b2f(hi));
}

// ---- A = relu(h1 @ W2 + b2) via 3-way split MFMA.
// LDS-staged 128(M) x 128(N) block tile, BK=64 two-phase, 2x2 wave grid
// (each wave 64x64 out). Padded LDS stride (72 u16 = 144 B) makes both the
// staged ds_write_b128 and the fragment ds_read_b128 bank-uniform.
// Quantize per 16-edge x 128-n tile to u16 (scale combined across the two
// column waves -> bit-identical to previous kernel). Epilogue: LDS-staged
// coalesced dwordx4 stores (LDS reused, 136-u16 stride avoids conflicts). ----
#define LDK 72   // 64 + 8 pad (u16)
#define STK 136  // 128 + 8 pad (u16), keeps 16B alignment per row (272 B)

__global__ __launch_bounds__(256, 2) void k_gemmA(const float* __restrict__ b2,
                                                  u16* __restrict__ Aq) {
    __shared__ __align__(16) u16 smem[4 * 128 * LDK];  // 73728 B
    __shared__ float redmax[2][4][2];                  // [wm][mi][wn]
    u16 (*sAh)[LDK] = (u16(*)[LDK])smem;
    u16 (*sAl)[LDK] = (u16(*)[LDK])(smem + 128 * LDK);
    u16 (*sBh)[LDK] = (u16(*)[LDK])(smem + 2 * 128 * LDK);
    u16 (*sBl)[LDK] = (u16(*)[LDK])(smem + 3 * 128 * LDK);
    u16 (*st)[STK]  = (u16(*)[STK])smem;               // 34816 B, fits

    // bijective XCD swizzle: 16000 blocks = 8 XCDs x 2000; consecutive
    // logical ids (which share an h1 tile, cb-fast) stay on one XCD.
    int bid = (blockIdx.x & 7) * 2000 + (blockIdx.x >> 3);
    int cb = bid & 31;        // col-block fast: consecutive blocks share h1 tile
    int rb = bid >> 5;        // 0..499
    int m0 = rb * 128, n0 = cb * 128;
    int t = threadIdx.x;
    int w = t >> 6, l = t & 63;
    int wm = w >> 1, wn = w & 1;          // 2x2 wave grid
    int quad = l >> 4, lr = l & 15;

    float4v acc[4][4];
#pragma unroll
    for (int mi = 0; mi < 4; mi++)
#pragma unroll
        for (int ni = 0; ni < 4; ni++) acc[mi][ni] = (float4v){0.f, 0.f, 0.f, 0.f};

#pragma unroll
    for (int kc = 0; kc < 2; kc++) {
        if (kc) __syncthreads();  // previous phase's reads done before overwrite
        // stage: per plane 128 rows x 64 u16 (128 B) = 1024 x 16B chunks
#pragma unroll
        for (int rnd = 0; rnd < 4; rnd++) {
            int c = rnd * 256 + t;
            int row = c >> 3, c8 = c & 7;       // 8 x 16B chunks per row
            size_t gA = ((size_t)(m0 + row) << 7) + (kc << 6) + (c8 << 3);
            size_t gB = ((size_t)(n0 + row) << 7) + (kc << 6) + (c8 << 3);
            *(uint4*)&sAh[row][c8 * 8] = *(const uint4*)(g_h1_hi + gA);
            *(uint4*)&sAl[row][c8 * 8] = *(const uint4*)(g_h1_lo + gA);
            *(uint4*)&sBh[row][c8 * 8] = *(const uint4*)(g_w2t_hi + gB);
            *(uint4*)&sBl[row][c8 * 8] = *(const uint4*)(g_w2t_lo + gB);
        }
        __syncthreads();
#pragma unroll
        for (int kq = 0; kq < 2; kq++) {
            int ko = kq * 32 + quad * 8;
            bf16x8 ah[4], al[4], bh[4], bl[4];
#pragma unroll
            for (int i = 0; i < 4; i++) {
                ah[i] = *(const bf16x8*)&sAh[wm * 64 + i * 16 + lr][ko];
                al[i] = *(const bf16x8*)&sAl[wm * 64 + i * 16 + lr][ko];
                bh[i] = *(const bf16x8*)&sBh[wn * 64 + i * 16 + lr][ko];
                bl[i] = *(const bf16x8*)&sBl[wn * 64 + i * 16 + lr][ko];
            }
#pragma unroll
            for (int mi = 0; mi < 4; mi++)
#pragma unroll
                for (int ni = 0; ni < 4; ni++) {
                    acc[mi][ni] = __builtin_amdgcn_mfma_f32_16x16x32_bf16(ah[mi], bh[ni], acc[mi][ni], 0, 0, 0);
                    acc[mi][ni] = __builtin_amdgcn_mfma_f32_16x16x32_bf16(ah[mi], bl[ni], acc[mi][ni], 0, 0, 0);
                    acc[mi][ni] = __builtin_amdgcn_mfma_f32_16x16x32_bf16(al[mi], bh[ni], acc[mi][ni], 0, 0, 0);
                }
        }
    }

    // bias + relu in place; per-(16-row x 64-col) wave max, per mi
    float wmax[4];
#pragma unroll
    for (int mi = 0; mi < 4; mi++) {
        float lm = 0.f;
#pragma unroll
        for (int ni = 0; ni < 4; ni++) {
            float bias = b2[n0 + wn * 64 + ni * 16 + lr];
#pragma unroll
            for (int r = 0; r < 4; r++) {
                float v = fmaxf(acc[mi][ni][r] + bias, 0.f);
                acc[mi][ni][r] = v;
                lm = fmaxf(lm, v);
            }
        }
#pragma unroll
        for (int ofs = 32; ofs > 0; ofs >>= 1)
            lm = fmaxf(lm, __shfl_xor(lm, ofs));
        wmax[mi] = lm;
    }
    if (l == 0) {
#pragma unroll
        for (int mi = 0; mi < 4; mi++) redmax[wm][mi][wn] = wmax[mi];
    }
    __syncthreads();  // redmax visible; also: all MFMA reads of smem done

    float inv[4];
#pragma unroll
    for (int mi = 0; mi < 4; mi++) {
        float cm = fmaxf(redmax[wm][mi][0], redmax[wm][mi][1]);
        inv[mi] = (cm > 0.f) ? (65535.f / cm) : 0.f;
        if (wn == 0 && l == 0)
            g_scale[(size_t)((m0 + wm * 64 + mi * 16) >> 4) * 32 + cb] = cm * (1.f / 65535.f);
    }

    // quantize into LDS staging tile (128 x 128, padded stride)
#pragma unroll
    for (int mi = 0; mi < 4; mi++)
#pragma unroll
        for (int ni = 0; ni < 4; ni++) {
            int col = wn * 64 + ni * 16 + lr;
#pragma unroll
            for (int r = 0; r < 4; r++) {
                u16 q = (u16)fminf(acc[mi][ni][r] * inv[mi] + 0.5f, 65535.f);
                st[wm * 64 + mi * 16 + quad * 4 + r][col] = q;
            }
        }
    __syncthreads();

    // coalesced stores: 128 rows x 256 B, 2048 chunks / 256 threads
#pragma unroll
    for (int rnd = 0; rnd < 8; rnd++) {
        int c = rnd * 256 + t;
        int row = c >> 4, ch = c & 15;
        uint4 v = *(const uint4*)&st[row][ch * 8];
        *(uint4*)(Aq + (size_t)(m0 + row) * HH + n0 + ch * 8) = v;
    }
}

// ---- per step: one wave per edge, fully-coalesced Aq reads + 8-lane
// butterfly reduction. msg = A_e @ x[src], scatter to m[tgt], m[src].
// All 8 row-loads hoisted (8-deep MLP) and nontemporal: Aq is a 524 MB
// stream with zero cache value — don't evict x/edges/g_scale from L2. ----
__global__ __launch_bounds__(256) void k_edge(const u16* __restrict__ Aq,
                                              const float* __restrict__ xcur,
                                              const int* __restrict__ edges,
                                              float* __restrict__ m) {
    int gid = blockIdx.x * 256 + threadIdx.x;
    int e = gid >> 6;
    int l = gid & 63;
    int src = edges[2 * e], tgt = edges[2 * e + 1];
    // lane l's x chunk: cols [(l&7)*8, +8) — invariant across t
    const float4* xp = (const float4*)(xcur + (size_t)src * HD + (l & 7) * 8);
    float4 xa = xp[0], xb = xp[1];
    const uint4v* ap = (const uint4v*)(Aq + (size_t)e * HH);  // 8KB row-major edge matrix
    uint4v a[8];
#pragma unroll
    for (int t = 0; t < 8; t++)
        a[t] = __builtin_nontemporal_load(&ap[t * 64 + l]);
    float msgv = 0.f;
#pragma unroll
    for (int t = 0; t < 8; t++) {
        // lane l holds flat u16 [t*512 + l*8, +8): row 8t+(l>>3), cols (l&7)*8..+8
        float p;
        p  = (float)(a[t].x & 0xFFFFu) * xa.x + (float)(a[t].x >> 16) * xa.y;
        p += (float)(a[t].y & 0xFFFFu) * xa.z + (float)(a[t].y >> 16) * xa.w;
        p += (float)(a[t].z & 0xFFFFu) * xb.x + (float)(a[t].z >> 16) * xb.y;
        p += (float)(a[t].w & 0xFFFFu) * xb.z + (float)(a[t].w >> 16) * xb.w;
        // reduce over the 8 lanes sharing this row (same l>>3)
        p += __shfl_xor(p, 1);
        p += __shfl_xor(p, 2);
        p += __shfl_xor(p, 4);
        msgv = ((l & 7) == t) ? p : msgv;
    }
    int r = (l & 7) * 8 + (l >> 3);  // row this lane ended up owning (bijection)
    float scale = g_scale[(e >> 4) * 32 + (r >> 1)];
    float msg = msgv * scale;
    unsafeAtomicAdd(&m[(size_t)tgt * HD + r], msg);
    if (src != tgt) unsafeAtomicAdd(&m[(size_t)src * HD + r], msg);
}

// ---- per step: GRU update per node. 256 threads/node: the K=64 inner
// reduction is split across 4 sub-waves (16 iters each, 4x shorter dep
// chains), partials combined through LDS, wave 0 does the nonlinearity.
// 8000 waves chip-wide (was 2000) -> occupancy-driven latency hiding.
// Re-zeroes m for the next step's atomics; fp32 out on last step. ----
__global__ __launch_bounds__(256) void k_gru(const float* __restrict__ xcur,
                                             float* __restrict__ m,
                                             const float* __restrict__ W_ih,
                                             const float* __restrict__ W_hh,
                                             const float* __restrict__ b_ih,
                                             const float* __restrict__ b_hh,
                                             float* __restrict__ xnext,
                                             float* __restrict__ out, int write_out) {
    int v = blockIdx.x;
    int tid = threadIdx.x;
    int j = tid & 63;        // output column
    int kq = tid >> 6;       // k-quarter 0..3
    __shared__ float xs[HD], ms[HD];
    __shared__ float red[4][6][HD];
    if (tid < HD) {
        xs[tid] = xcur[v * HD + tid];
        ms[tid] = m[v * HD + tid];
    }
    __syncthreads();
    float gir = 0.f, giz = 0.f, gin = 0.f;
    float ghr = 0.f, ghz = 0.f, ghn = 0.f;
#pragma unroll
    for (int ki = 0; ki < 16; ki++) {
        int k = kq * 16 + ki;
        float xk = xs[k], mk = ms[k];
        const float* wi_x = W_ih + k * 192;
        const float* wi_m = W_ih + (64 + k) * 192;
        const float* wh = W_hh + k * 192;
        gir += xk * wi_x[j] + mk * wi_m[j];
        giz += xk * wi_x[64 + j] + mk * wi_m[64 + j];
        gin += xk * wi_x[128 + j] + mk * wi_m[128 + j];
        ghr += xk * wh[j];
        ghz += xk * wh[64 + j];
        ghn += xk * wh[128 + j];
    }
    red[kq][0][j] = gir; red[kq][1][j] = giz; red[kq][2][j] = gin;
    red[kq][3][j] = ghr; red[kq][4][j] = ghz; red[kq][5][j] = ghn;
    __syncthreads();
    if (kq == 0) {
        float sgir = b_ih[j]       + red[0][0][j] + red[1][0][j] + red[2][0][j] + red[3][0][j];
        float sgiz = b_ih[64 + j]  + red[0][1][j] + red[1][1][j] + red[2][1][j] + red[3][1][j];
        float sgin = b_ih[128 + j] + red[0][2][j] + red[1][2][j] + red[2][2][j] + red[3][2][j];
        float sghr = b_hh[j]       + red[0][3][j] + red[1][3][j] + red[2][3][j] + red[3][3][j];
        float sghz = b_hh[64 + j]  + red[0][4][j] + red[1][4][j] + red[2][4][j] + red[3][4][j];
        float sghn = b_hh[128 + j] + red[0][5][j] + red[1][5][j] + red[2][5][j] + red[3][5][j];
        float r = 1.f / (1.f + __expf(-(sgir + sghr)));
        float z = 1.f / (1.f + __expf(-(sgiz + sghz)));
        float n = tanhf(sgin + r * sghn);
        float xn = (1.f - z) * n + z * xs[j];
        xnext[v * HD + j] = xn;
        m[v * HD + j] = 0.f;  // ready for next step's atomics
        if (write_out) out[v * HD + j] = xn;
    }
}

extern "C" void kernel_launch(void* const* d_in, const int* in_sizes, int n_in,
                              void* d_out, int out_size, void* d_ws, size_t ws_size,
                              hipStream_t stream) {
    (void)in_sizes; (void)n_in; (void)out_size; (void)ws_size;
    const float* x_in      = (const float*)d_in[0];
    // d_in[1] adj: unused (zeros)
    const float* edge_data = (const float*)d_in[2];
    const int*   edges     = (const int*)d_in[3];
    // d_in[4] T: fixed at 8 (module constant in reference)
    const float* W1   = (const float*)d_in[5];
    const float* b1   = (const float*)d_in[6];
    const float* W2   = (const float*)d_in[7];
    const float* b2   = (const float*)d_in[8];
    const float* W_ih = (const float*)d_in[9];
    const float* W_hh = (const float*)d_in[10];
    const float* b_ih = (const float*)d_in[11];
    const float* b_hh = (const float*)d_in[12];
    float* out = (float*)d_out;

    // d_ws layout: Aq (524.3 MB) + x ping-pong + m (1.5 MB)
    char* ws = (char*)d_ws;
    u16* Aq = (u16*)ws;
    size_t off = (size_t)N_EDGES * HH * sizeof(u16);
    float* xb0 = (float*)(ws + off); off += (size_t)N_NODES * HD * sizeof(float);
    float* xb1 = (float*)(ws + off); off += (size_t)N_NODES * HD * sizeof(float);
    float* m   = (float*)(ws + off); off += (size_t)N_NODES * HD * sizeof(float);

    k_xinit<<<(N_NODES * HD + 255) / 256, 256, 0, stream>>>(x_in, xb0, m);
    k_h1<<<N_EDGES / 2, 256, 0, stream>>>(edge_data, edges, W1, b1);
    k_w2t<<<(HH * 128) / 256, 256, 0, stream>>>(W2);
    k_gemmA<<<(N_EDGES / 128) * (HH / 128), 256, 0, stream>>>(b2, Aq);

    float* bufs[2] = {xb0, xb1};
    for (int t = 0; t < T_STEPS; t++) {
        k_edge<<<(N_EDGES * 64) / 256, 256, 0, stream>>>(Aq, bufs[t & 1], edges, m);
        k_gru<<<N_NODES, 256, 0, stream>>>(bufs[t & 1], m, W_ih, W_hh, b_ih, b_hh,
                                           bufs[(t + 1) & 1], out,
                                           (t == T_STEPS - 1) ? 1 : 0);
    }
}

// Round 5
// 1445.582 us; speedup vs baseline: 1.5517x; 1.0077x over previous
//
#include <hip/hip_runtime.h>
#include <stdint.h>

#define N_NODES 2000
#define N_EDGES 64000
#define EDIM 16
#define ENH 128
#define HD 64
#define T_STEPS 8
#define HH 4096  // HD*HD

typedef unsigned short u16;
typedef __bf16 bf16x8 __attribute__((ext_vector_type(8)));
typedef float float4v __attribute__((ext_vector_type(4)));
typedef unsigned int uint4v __attribute__((ext_vector_type(4)));  // native vec for nontemporal builtins

// ---- static device scratch (rewritten every call); d_ws holds Aq + x/m ----
__device__ u16   g_h1_hi[(size_t)N_EDGES * ENH];   // 16.4 MB
__device__ u16   g_h1_lo[(size_t)N_EDGES * ENH];   // 16.4 MB
__device__ u16   g_w2t_hi[HH * ENH];               // 1 MB
__device__ u16   g_w2t_lo[HH * ENH];               // 1 MB
__device__ float g_scale[(N_EDGES / 16) * 32];     // per 16-edge x 128-n tile scale

__device__ __forceinline__ float b2f(u16 h) {
    union { unsigned int u; float f; } v; v.u = ((unsigned int)h) << 16; return v.f;
}
__device__ __forceinline__ u16 f2b(float f) {
    union { float f; unsigned int u; } v; v.f = f;
    unsigned int u = v.u;
    return (u16)((u + 0x7FFFu + ((u >> 16) & 1u)) >> 16);  // RNE
}

// async global->LDS DMA, 16B per lane. LDS dest = wave-uniform base + lane*16
// (pass identical lptr across the wave); global src is per-lane.
__device__ __forceinline__ void gld_lds16(const void* g, void* l) {
    __builtin_amdgcn_global_load_lds(
        (const __attribute__((address_space(1))) unsigned int*)(uintptr_t)g,
        (__attribute__((address_space(3))) unsigned int*)(unsigned int)(uintptr_t)l,
        16, 0, 0);
}

// ---- x fp32 -> ping-pong buffer; also zero m for the first step's atomics ----
__global__ void k_xinit(const float* __restrict__ xin, float* __restrict__ x0,
                        float* __restrict__ m) {
    int i = blockIdx.x * 256 + threadIdx.x;
    if (i < N_NODES * HD) { x0[i] = xin[i]; m[i] = 0.f; }
}

// ---- h1 = relu(ef @ W1 + b1) in fp32, stored as exact bf16 hi+lo split ----
__global__ __launch_bounds__(256) void k_h1(const float* __restrict__ edge_data,
                                            const int* __restrict__ edges,
                                            const float* __restrict__ W1,
                                            const float* __restrict__ b1) {
    int tid = threadIdx.x;
    int e = blockIdx.x * 2 + (tid >> 7);
    int c = tid & 127;
    int src = edges[2 * e], tgt = edges[2 * e + 1];
    const float* ef = edge_data + ((size_t)src * N_NODES + (size_t)tgt) * EDIM;
    float acc = b1[c];
#pragma unroll
    for (int k = 0; k < EDIM; k++)
        acc += ef[k] * W1[k * ENH + c];
    float v = fmaxf(acc, 0.f);
    u16 hi = f2b(v);
    size_t idx = (size_t)e * ENH + c;
    g_h1_hi[idx] = hi;
    g_h1_lo[idx] = f2b(v - b2f(hi));
}

// ---- W2 (128 x 4096) -> transposed bf16 hi/lo planes (k-contiguous) ----
__global__ void k_w2t(const float* __restrict__ W2) {
    int idx = blockIdx.x * 256 + threadIdx.x;  // = n*128 + k
    int n = idx >> 7, k = idx & 127;
    float v = W2[(size_t)k * HH + n];
    u16 hi = f2b(v);
    g_w2t_hi[idx] = hi;
    g_w2t_lo[idx] = f2b(v - b2f(hi));
}

// ---- A = relu(h1 @ W2 + b2) via 3-way split MFMA.
// 128(M) x 128(N) block tile, BK=64 two-phase, 2x2 wave grid (64x64/wave).
// Staging via global_load_lds (16B DMA, no VGPR roundtrip) into LINEAR
// [128][64] u16 planes, with both-sides XOR swizzle (chunk ^= row&7 applied
// to the global source at stage time and to the ds_read chunk at fragment
// time) -> bank-quad index (4kq+quad)^(lr&7) is uniform: conflict-free.
// Quantize per 16-edge x 128-n tile to u16 (scale combined across the two
// column waves). Epilogue: LDS-staged coalesced dwordx4 stores (LDS reused,
// 136-u16 stride). ----
#define LDSPLANE 8192  // u16 per plane: 128 rows x 64
#define STK 136        // 128 + 8 pad (u16), keeps 16B alignment per row (272 B)

__global__ __launch_bounds__(256, 2) void k_gemmA(const float* __restrict__ b2,
                                                  u16* __restrict__ Aq) {
    __shared__ __align__(16) u16 smem[4 * LDSPLANE];   // 65536 B
    __shared__ float redmax[2][4][2];                  // [wm][mi][wn]
    u16* sAh = smem;
    u16* sAl = smem + LDSPLANE;
    u16* sBh = smem + 2 * LDSPLANE;
    u16* sBl = smem + 3 * LDSPLANE;
    u16 (*st)[STK] = (u16(*)[STK])smem;                // 34816 B, fits

    // bijective XCD swizzle: 16000 blocks = 8 XCDs x 2000; consecutive
    // logical ids (which share an h1 tile, cb-fast) stay on one XCD.
    int bid = (blockIdx.x & 7) * 2000 + (blockIdx.x >> 3);
    int cb = bid & 31;        // col-block fast: consecutive blocks share h1 tile
    int rb = bid >> 5;        // 0..499
    int m0 = rb * 128, n0 = cb * 128;
    int t = threadIdx.x;
    int w = t >> 6, l = t & 63;
    int wm = w >> 1, wn = w & 1;          // 2x2 wave grid
    int quad = l >> 4, lr = l & 15;

    float4v acc[4][4];
#pragma unroll
    for (int mi = 0; mi < 4; mi++)
#pragma unroll
        for (int ni = 0; ni < 4; ni++) acc[mi][ni] = (float4v){0.f, 0.f, 0.f, 0.f};

    int rowl = l >> 3;   // 0..7 within a 1KB DMA issue
    int c8 = l & 7;      // 16B chunk within the row's 128B half-K

#pragma unroll
    for (int kc = 0; kc < 2; kc++) {
        if (kc) __syncthreads();  // previous phase's reads done before overwrite
        // DMA stage: wave w covers rows [w*32, w*32+32) of all 4 planes.
        // Global chunk pre-swizzled (cs = c8 ^ row&7) so linear LDS + swizzled
        // read reproduce the same involution (rule: both-sides-or-neither).
#pragma unroll
        for (int i = 0; i < 4; i++) {
            int r0 = w * 32 + i * 8;
            int row = r0 + rowl;
            int cs = c8 ^ (row & 7);
            size_t offA = ((size_t)(m0 + row) << 8) + ((size_t)kc << 7) + ((size_t)cs << 4);
            size_t offB = ((size_t)(n0 + row) << 8) + ((size_t)kc << 7) + ((size_t)cs << 4);
            size_t lofs = (size_t)r0 << 7;  // r0*128 bytes within plane
            gld_lds16((const char*)g_h1_hi + offA, (char*)sAh + lofs);
            gld_lds16((const char*)g_h1_lo + offA, (char*)sAl + lofs);
            gld_lds16((const char*)g_w2t_hi + offB, (char*)sBh + lofs);
            gld_lds16((const char*)g_w2t_lo + offB, (char*)sBl + lofs);
        }
        __syncthreads();  // vmcnt(0) drain: DMA data visible in LDS
#pragma unroll
        for (int kq = 0; kq < 2; kq++) {
            bf16x8 ah[4], al[4], bh[4], bl[4];
            int cl = (4 * kq + quad) ^ (lr & 7);   // swizzled 16B chunk
            size_t cb16 = (size_t)(cl << 4);
#pragma unroll
            for (int i = 0; i < 4; i++) {
                size_t ra = (size_t)(wm * 64 + i * 16 + lr) << 7;  // row*128 B
                size_t rbb = (size_t)(wn * 64 + i * 16 + lr) << 7;
                ah[i] = *(const bf16x8*)((const char*)sAh + ra + cb16);
                al[i] = *(const bf16x8*)((const char*)sAl + ra + cb16);
                bh[i] = *(const bf16x8*)((const char*)sBh + rbb + cb16);
                bl[i] = *(const bf16x8*)((const char*)sBl + rbb + cb16);
            }
#pragma unroll
            for (int mi = 0; mi < 4; mi++)
#pragma unroll
                for (int ni = 0; ni < 4; ni++) {
                    acc[mi][ni] = __builtin_amdgcn_mfma_f32_16x16x32_bf16(ah[mi], bh[ni], acc[mi][ni], 0, 0, 0);
                    acc[mi][ni] = __builtin_amdgcn_mfma_f32_16x16x32_bf16(ah[mi], bl[ni], acc[mi][ni], 0, 0, 0);
                    acc[mi][ni] = __builtin_amdgcn_mfma_f32_16x16x32_bf16(al[mi], bh[ni], acc[mi][ni], 0, 0, 0);
                }
        }
    }

    // bias + relu in place; per-(16-row x 64-col) wave max, per mi
    float wmax[4];
#pragma unroll
    for (int mi = 0; mi < 4; mi++) {
        float lm = 0.f;
#pragma unroll
        for (int ni = 0; ni < 4; ni++) {
            float bias = b2[n0 + wn * 64 + ni * 16 + lr];
#pragma unroll
            for (int r = 0; r < 4; r++) {
                float v = fmaxf(acc[mi][ni][r] + bias, 0.f);
                acc[mi][ni][r] = v;
                lm = fmaxf(lm, v);
            }
        }
#pragma unroll
        for (int ofs = 32; ofs > 0; ofs >>= 1)
            lm = fmaxf(lm, __shfl_xor(lm, ofs));
        wmax[mi] = lm;
    }
    if (l == 0) {
#pragma unroll
        for (int mi = 0; mi < 4; mi++) redmax[wm][mi][wn] = wmax[mi];
    }
    __syncthreads();  // redmax visible; also: all MFMA reads of smem done

    float inv[4];
#pragma unroll
    for (int mi = 0; mi < 4; mi++) {
        float cm = fmaxf(redmax[wm][mi][0], redmax[wm][mi][1]);
        inv[mi] = (cm > 0.f) ? (65535.f / cm) : 0.f;
        if (wn == 0 && l == 0)
            g_scale[(size_t)((m0 + wm * 64 + mi * 16) >> 4) * 32 + cb] = cm * (1.f / 65535.f);
    }

    // quantize into LDS staging tile (128 x 128, padded stride)
#pragma unroll
    for (int mi = 0; mi < 4; mi++)
#pragma unroll
        for (int ni = 0; ni < 4; ni++) {
            int col = wn * 64 + ni * 16 + lr;
#pragma unroll
            for (int r = 0; r < 4; r++) {
                u16 q = (u16)fminf(acc[mi][ni][r] * inv[mi] + 0.5f, 65535.f);
                st[wm * 64 + mi * 16 + quad * 4 + r][col] = q;
            }
        }
    __syncthreads();

    // coalesced stores: 128 rows x 256 B, 2048 chunks / 256 threads
#pragma unroll
    for (int rnd = 0; rnd < 8; rnd++) {
        int c = rnd * 256 + t;
        int row = c >> 4, ch = c & 15;
        uint4 v = *(const uint4*)&st[row][ch * 8];
        *(uint4*)(Aq + (size_t)(m0 + row) * HH + n0 + ch * 8) = v;
    }
}

// ---- per step: one wave per edge, fully-coalesced Aq reads + 8-lane
// butterfly reduction. msg = A_e @ x[src], scatter to m[tgt], m[src].
// All 8 row-loads hoisted (8-deep MLP) and nontemporal: Aq is a 524 MB
// stream with zero cache value — don't evict x/edges/g_scale from L2. ----
__global__ __launch_bounds__(256) void k_edge(const u16* __restrict__ Aq,
                                              const float* __restrict__ xcur,
                                              const int* __restrict__ edges,
                                              float* __restrict__ m) {
    int gid = blockIdx.x * 256 + threadIdx.x;
    int e = gid >> 6;
    int l = gid & 63;
    int src = edges[2 * e], tgt = edges[2 * e + 1];
    // lane l's x chunk: cols [(l&7)*8, +8) — invariant across t
    const float4* xp = (const float4*)(xcur + (size_t)src * HD + (l & 7) * 8);
    float4 xa = xp[0], xb = xp[1];
    const uint4v* ap = (const uint4v*)(Aq + (size_t)e * HH);  // 8KB row-major edge matrix
    uint4v a[8];
#pragma unroll
    for (int t = 0; t < 8; t++)
        a[t] = __builtin_nontemporal_load(&ap[t * 64 + l]);
    float msgv = 0.f;
#pragma unroll
    for (int t = 0; t < 8; t++) {
        // lane l holds flat u16 [t*512 + l*8, +8): row 8t+(l>>3), cols (l&7)*8..+8
        float p;
        p  = (float)(a[t].x & 0xFFFFu) * xa.x + (float)(a[t].x >> 16) * xa.y;
        p += (float)(a[t].y & 0xFFFFu) * xa.z + (float)(a[t].y >> 16) * xa.w;
        p += (float)(a[t].z & 0xFFFFu) * xb.x + (float)(a[t].z >> 16) * xb.y;
        p += (float)(a[t].w & 0xFFFFu) * xb.z + (float)(a[t].w >> 16) * xb.w;
        // reduce over the 8 lanes sharing this row (same l>>3)
        p += __shfl_xor(p, 1);
        p += __shfl_xor(p, 2);
        p += __shfl_xor(p, 4);
        msgv = ((l & 7) == t) ? p : msgv;
    }
    int r = (l & 7) * 8 + (l >> 3);  // row this lane ended up owning (bijection)
    float scale = g_scale[(e >> 4) * 32 + (r >> 1)];
    float msg = msgv * scale;
    unsafeAtomicAdd(&m[(size_t)tgt * HD + r], msg);
    if (src != tgt) unsafeAtomicAdd(&m[(size_t)src * HD + r], msg);
}

// ---- per step: GRU update per node. 256 threads/node: the K=64 inner
// reduction is split across 4 sub-waves (16 iters each, 4x shorter dep
// chains), partials combined through LDS, wave 0 does the nonlinearity.
// 8000 waves chip-wide (was 2000) -> occupancy-driven latency hiding.
// Re-zeroes m for the next step's atomics; fp32 out on last step. ----
__global__ __launch_bounds__(256) void k_gru(const float* __restrict__ xcur,
                                             float* __restrict__ m,
                                             const float* __restrict__ W_ih,
                                             const float* __restrict__ W_hh,
                                             const float* __restrict__ b_ih,
                                             const float* __restrict__ b_hh,
                                             float* __restrict__ xnext,
                                             float* __restrict__ out, int write_out) {
    int v = blockIdx.x;
    int tid = threadIdx.x;
    int j = tid & 63;        // output column
    int kq = tid >> 6;       // k-quarter 0..3
    __shared__ float xs[HD], ms[HD];
    __shared__ float red[4][6][HD];
    if (tid < HD) {
        xs[tid] = xcur[v * HD + tid];
        ms[tid] = m[v * HD + tid];
    }
    __syncthreads();
    float gir = 0.f, giz = 0.f, gin = 0.f;
    float ghr = 0.f, ghz = 0.f, ghn = 0.f;
#pragma unroll
    for (int ki = 0; ki < 16; ki++) {
        int k = kq * 16 + ki;
        float xk = xs[k], mk = ms[k];
        const float* wi_x = W_ih + k * 192;
        const float* wi_m = W_ih + (64 + k) * 192;
        const float* wh = W_hh + k * 192;
        gir += xk * wi_x[j] + mk * wi_m[j];
        giz += xk * wi_x[64 + j] + mk * wi_m[64 + j];
        gin += xk * wi_x[128 + j] + mk * wi_m[128 + j];
        ghr += xk * wh[j];
        ghz += xk * wh[64 + j];
        ghn += xk * wh[128 + j];
    }
    red[kq][0][j] = gir; red[kq][1][j] = giz; red[kq][2][j] = gin;
    red[kq][3][j] = ghr; red[kq][4][j] = ghz; red[kq][5][j] = ghn;
    __syncthreads();
    if (kq == 0) {
        float sgir = b_ih[j]       + red[0][0][j] + red[1][0][j] + red[2][0][j] + red[3][0][j];
        float sgiz = b_ih[64 + j]  + red[0][1][j] + red[1][1][j] + red[2][1][j] + red[3][1][j];
        float sgin = b_ih[128 + j] + red[0][2][j] + red[1][2][j] + red[2][2][j] + red[3][2][j];
        float sghr = b_hh[j]       + red[0][3][j] + red[1][3][j] + red[2][3][j] + red[3][3][j];
        float sghz = b_hh[64 + j]  + red[0][4][j] + red[1][4][j] + red[2][4][j] + red[3][4][j];
        float sghn = b_hh[128 + j] + red[0][5][j] + red[1][5][j] + red[2][5][j] + red[3][5][j];
        float r = 1.f / (1.f + __expf(-(sgir + sghr)));
        float z = 1.f / (1.f + __expf(-(sgiz + sghz)));
        float n = tanhf(sgin + r * sghn);
        float xn = (1.f - z) * n + z * xs[j];
        xnext[v * HD + j] = xn;
        m[v * HD + j] = 0.f;  // ready for next step's atomics
        if (write_out) out[v * HD + j] = xn;
    }
}

extern "C" void kernel_launch(void* const* d_in, const int* in_sizes, int n_in,
                              void* d_out, int out_size, void* d_ws, size_t ws_size,
                              hipStream_t stream) {
    (void)in_sizes; (void)n_in; (void)out_size; (void)ws_size;
    const float* x_in      = (const float*)d_in[0];
    // d_in[1] adj: unused (zeros)
    const float* edge_data = (const float*)d_in[2];
    const int*   edges     = (const int*)d_in[3];
    // d_in[4] T: fixed at 8 (module constant in reference)
    const float* W1   = (const float*)d_in[5];
    const float* b1   = (const float*)d_in[6];
    const float* W2   = (const float*)d_in[7];
    const float* b2   = (const float*)d_in[8];
    const float* W_ih = (const float*)d_in[9];
    const float* W_hh = (const float*)d_in[10];
    const float* b_ih = (const float*)d_in[11];
    const float* b_hh = (const float*)d_in[12];
    float* out = (float*)d_out;

    // d_ws layout: Aq (524.3 MB) + x ping-pong + m (1.5 MB)
    char* ws = (char*)d_ws;
    u16* Aq = (u16*)ws;
    size_t off = (size_t)N_EDGES * HH * sizeof(u16);
    float* xb0 = (float*)(ws + off); off += (size_t)N_NODES * HD * sizeof(float);
    float* xb1 = (float*)(ws + off); off += (size_t)N_NODES * HD * sizeof(float);
    float* m   = (float*)(ws + off); off += (size_t)N_NODES * HD * sizeof(float);

    k_xinit<<<(N_NODES * HD + 255) / 256, 256, 0, stream>>>(x_in, xb0, m);
    k_h1<<<N_EDGES / 2, 256, 0, stream>>>(edge_data, edges, W1, b1);
    k_w2t<<<(HH * 128) / 256, 256, 0, stream>>>(W2);
    k_gemmA<<<(N_EDGES / 128) * (HH / 128), 256, 0, stream>>>(b2, Aq);

    float* bufs[2] = {xb0, xb1};
    for (int t = 0; t < T_STEPS; t++) {
        k_edge<<<(N_EDGES * 64) / 256, 256, 0, stream>>>(Aq, bufs[t & 1], edges, m);
        k_gru<<<N_NODES, 256, 0, stream>>>(bufs[t & 1], m, W_ih, W_hh, b_ih, b_hh,
                                           bufs[(t + 1) & 1], out,
                                           (t == T_STEPS - 1) ? 1 : 0);
    }
}